// Round 13
// baseline (104.970 us; speedup 1.0000x reference)
//
#include <hip/hip_runtime.h>

// TopKRouter: N=32768 tokens, D=2048, E=64, K=2.
// R13 = R12 minus all K-loop barriers/LDS: w-fragments are read per-lane
// directly from global (L1/L2-resident, coalesced 1KB per (t,plane)), double-
// buffered in named registers one step ahead. K-loop = loads + cvt + MFMA
// only; waves fully independent; x HBM stream is the roofline.

#define NTOK 32768
#define DDIM 2048
#define NEXP 64
#define NKS 64              // K steps of 32
#define LG_STRIDE 68        // 64 + 4 pad

#define OFF_IDX 0
#define OFF_W 65536
#define OFF_CNT 131072
#define OFF_OVF 131136
#define OFF_ZL 131137
#define OFF_ENT 131138
#define OFF_VAR 131139
#define OFF_CONF 131140

#define WS_PLANES_OFF 1024
#define WS_NEEDED (WS_PLANES_OFF + NKS * 8192)  // 1 KB + 512 KB

struct RouterWS {
  unsigned int counts[NEXP];
  double z_sum;
  double ent_sum;
};

typedef _Float16 half8 __attribute__((ext_vector_type(8)));
typedef float floatx4 __attribute__((ext_vector_type(4)));

// ---- prologue: split w*256 into 2 fp16 planes, fragment-ordered ----
// plane layout (halves): [s][p][t][l][8] ; s=kstep, p=plane, t=etile, l=lane.
// lane l of etile t reads w[e=16t+(l&15)][k=32s+(l>>4)*8 .. +7].
__global__ void convert_w(const float* __restrict__ w, _Float16* __restrict__ wp) {
  int tid = blockIdx.x * 256 + threadIdx.x;  // 0..16383
  int l = tid & 63;
  int t = (tid >> 6) & 3;
  int s = tid >> 8;
  int e = 16 * t + (l & 15);
  int k0 = 32 * s + (l >> 4) * 8;
  const float* src = w + (size_t)e * DDIM + k0;
  half8 h, lo;
#pragma unroll
  for (int i = 0; i < 8; ++i) {
    float v = src[i] * 256.0f;
    _Float16 hh = (_Float16)v;
    h[i] = hh;
    lo[i] = (_Float16)(v - (float)hh);
  }
  size_t base = (size_t)s * 4096 + ((size_t)t * 64 + l) * 8;
  *(half8*)(wp + base) = h;
  *(half8*)(wp + base + 2048) = lo;  // plane 1
}

// ---- main MFMA kernel: no barriers, no LDS in the K loop ----
__global__ __launch_bounds__(256, 2) void router_mfma(
    const float* __restrict__ x, const _Float16* __restrict__ wp,
    float* __restrict__ out, RouterWS* __restrict__ ws) {
  __shared__ float lg[64 * LG_STRIDE];
  __shared__ unsigned int hist[NEXP];

  const int tid = threadIdx.x;                              // 0..255
  const int l = tid & 63;
  const int wv = __builtin_amdgcn_readfirstlane(tid >> 6);  // mtile 0..3
  const int r = l & 15;                                     // token row / expert col
  const int g = l >> 4;                                     // k-group

  const int tokb = blockIdx.x * 64;
  const float* xrow = x + (size_t)(tokb + wv * 16 + r) * DDIM + g * 8;
  const _Float16* wl8 = wp + (size_t)l * 8;  // lane's fragment base

  floatx4 acc[4];
#pragma unroll
  for (int t = 0; t < 4; ++t) {
    floatx4 z = {0.f, 0.f, 0.f, 0.f};
    acc[t] = z;
  }

  // prologue: x frags for steps 0,1 ; w frags for step 0 (regs, no LDS)
  float4 xA0 = *(const float4*)(xrow + 0);
  float4 xA1 = *(const float4*)(xrow + 4);
  float4 xB0 = *(const float4*)(xrow + 32);
  float4 xB1 = *(const float4*)(xrow + 36);
  half8 wA[8], wB[8];  // [2t]=hi plane, [2t+1]=lo plane; static indexing only
#pragma unroll
  for (int t = 0; t < 4; ++t) {
    wA[2 * t] = *(const half8*)(wl8 + t * 512);
    wA[2 * t + 1] = *(const half8*)(wl8 + 2048 + t * 512);
  }

#define CVT8(X0, X1, XH, XL)                                                   \
  {                                                                            \
    float vv[8] = {X0.x, X0.y, X0.z, X0.w, X1.x, X1.y, X1.z, X1.w};            \
    _Pragma("unroll") for (int i = 0; i < 8; ++i) {                            \
      _Float16 hh = (_Float16)vv[i];                                           \
      XH[i] = hh;                                                              \
      XL[i] = (_Float16)(vv[i] - (float)hh);                                   \
    }                                                                          \
  }

#define STEP(S, WCUR, WNXT, X0, X1)                                            \
  {                                                                            \
    const int s_ = (S);                                                        \
    if (s_ + 1 < NKS) { /* w depth-1 reg prefetch; L1/L2-hit, coalesced */     \
      const _Float16* sp = wl8 + (size_t)(s_ + 1) * 4096;                      \
      _Pragma("unroll") for (int t = 0; t < 4; ++t) {                          \
        WNXT[2 * t] = *(const half8*)(sp + t * 512);                           \
        WNXT[2 * t + 1] = *(const half8*)(sp + 2048 + t * 512);                \
      }                                                                        \
    }                                                                          \
    half8 xh, xl;                                                              \
    CVT8(X0, X1, xh, xl);                                                      \
    if (s_ + 2 < NKS) { /* x depth-2 prefetch; returns under MFMAs */          \
      X0 = *(const float4*)(xrow + (s_ + 2) * 32);                             \
      X1 = *(const float4*)(xrow + (s_ + 2) * 32 + 4);                         \
    }                                                                          \
    _Pragma("unroll") for (int t = 0; t < 4; ++t) { /* hh,hl,lh,ll = R12 */    \
      acc[t] = __builtin_amdgcn_mfma_f32_16x16x32_f16(xh, WCUR[2 * t],         \
                                                      acc[t], 0, 0, 0);        \
      acc[t] = __builtin_amdgcn_mfma_f32_16x16x32_f16(xh, WCUR[2 * t + 1],     \
                                                      acc[t], 0, 0, 0);        \
      acc[t] = __builtin_amdgcn_mfma_f32_16x16x32_f16(xl, WCUR[2 * t],         \
                                                      acc[t], 0, 0, 0);        \
      acc[t] = __builtin_amdgcn_mfma_f32_16x16x32_f16(xl, WCUR[2 * t + 1],     \
                                                      acc[t], 0, 0, 0);        \
    }                                                                          \
  }

  for (int ss = 0; ss < NKS; ss += 2) {
    STEP(ss, wA, wB, xA0, xA1);
    STEP(ss + 1, wB, wA, xB0, xB1);
  }
#undef STEP
#undef CVT8

  // C layout (HW-verified): col = lane&15, row = (lane>>4)*4 + j.
  // lg[token][expert], token = wv*16 + g*4 + j, expert = 16t + r. Scale 1/256.
#pragma unroll
  for (int t = 0; t < 4; ++t)
#pragma unroll
    for (int j = 0; j < 4; ++j)
      lg[(wv * 16 + g * 4 + j) * LG_STRIDE + 16 * t + r] = acc[t][j] * 0.00390625f;

  if (tid < NEXP) hist[tid] = 0;
  __syncthreads();

  if (tid < 64) {  // wave 0: one token per lane, serial over 64 experts
    const int t = tid;
    const float* Lg = &lg[t * LG_STRIDE];

    float m1 = Lg[0];
    int i1 = 0;
    for (int e = 1; e < NEXP; ++e) {
      float v = Lg[e];
      if (v > m1) { m1 = v; i1 = e; }  // strict > keeps lowest index on ties
    }
    float m2 = -3.4e38f;
    int i2 = 0;
    for (int e = 0; e < NEXP; ++e) {
      if (e == i1) continue;
      float v = Lg[e];
      if (v > m2) { m2 = v; i2 = e; }
    }

    float s = 0.f;
    for (int e = 0; e < NEXP; ++e) s += expf(Lg[e] - m1);
    float p1 = expf(Lg[i1] - m1) / s;
    float p2 = expf(Lg[i2] - m1) / s;
    float wsum = p1 + p2 + 1e-8f;
    float w1 = p1 / wsum;
    float w2 = p2 / wsum;

    float ent = 0.f;
    for (int e = 0; e < NEXP; ++e) {
      float p = expf(Lg[e] - m1) / s;
      ent -= p * logf(p + 1e-10f);
    }
    float lse = m1 + logf(s);

    size_t gt = (size_t)blockIdx.x * 64 + t;
    out[OFF_IDX + gt * 2 + 0] = (float)i1;
    out[OFF_IDX + gt * 2 + 1] = (float)i2;
    out[OFF_W + gt * 2 + 0] = w1;
    out[OFF_W + gt * 2 + 1] = w2;
    out[OFF_CONF + gt] = fmaxf(w1, w2);

    atomicAdd(&hist[i1], 1u);
    atomicAdd(&hist[i2], 1u);

    float zv = lse, ev = ent;
#pragma unroll
    for (int o = 32; o > 0; o >>= 1) {
      zv += __shfl_down(zv, o);
      ev += __shfl_down(ev, o);
    }
    if (t == 0) {
      atomicAdd(&ws->z_sum, (double)zv);
      atomicAdd(&ws->ent_sum, (double)ev);
    }
  }
  __syncthreads();
  if (tid < NEXP) atomicAdd(&ws->counts[tid], hist[tid]);
}

// ---- fp32 fallback (R10) if ws too small for planes ----
#define TTILE 128
#define KB 32
#define NCH (DDIM / KB)
#define XSTR 36
#define XBUF (TTILE * XSTR)
#define WBUF (NEXP * XSTR)
#define WOFF (2 * XBUF)

__global__ __launch_bounds__(512, 4) void router_fp32(
    const float* __restrict__ x, const float* __restrict__ w,
    float* __restrict__ out, RouterWS* __restrict__ ws) {
  __shared__ float smem[2 * XBUF + 2 * WBUF];
  __shared__ unsigned int hist[NEXP];

  const int tid = threadIdx.x;
  const int L = tid & 63;
  const int wv = __builtin_amdgcn_readfirstlane(tid >> 6);
  const float* xg = x + (size_t)blockIdx.x * TTILE * DDIM;
  const int sr = tid >> 3;
  const int sc = (tid & 7) * 4;

  float4 rx0 = *(const float4*)(xg + (size_t)sr * DDIM + sc);
  float4 rx1 = *(const float4*)(xg + (size_t)(sr + 64) * DDIM + sc);
  float4 rw = *(const float4*)(w + (size_t)sr * DDIM + sc);
  *(float4*)&smem[sr * XSTR + sc] = rx0;
  *(float4*)&smem[(sr + 64) * XSTR + sc] = rx1;
  *(float4*)&smem[WOFF + sr * XSTR + sc] = rw;

  float acc0[8], acc1[8];
#pragma unroll
  for (int e = 0; e < 8; ++e) { acc0[e] = 0.f; acc1[e] = 0.f; }
  __syncthreads();

  for (int c = 0; c < NCH; ++c) {
    const int cxb = (c & 1) * XBUF;
    const int cwb = WOFF + (c & 1) * WBUF;
    if (c + 1 < NCH) {
      int k0 = (c + 1) * KB;
      rx0 = *(const float4*)(xg + (size_t)sr * DDIM + k0 + sc);
      rx1 = *(const float4*)(xg + (size_t)(sr + 64) * DDIM + k0 + sc);
      rw = *(const float4*)(w + (size_t)sr * DDIM + k0 + sc);
    }
    float4 xr0[8], xr1[8];
#pragma unroll
    for (int m = 0; m < 8; ++m) {
      xr0[m] = *(const float4*)&smem[cxb + L * XSTR + 4 * m];
      xr1[m] = *(const float4*)&smem[cxb + (L + 64) * XSTR + 4 * m];
    }
#pragma unroll
    for (int e = 0; e < 8; ++e) {
      const float* wrow = &smem[cwb + (8 * wv + e) * XSTR];
      float a0 = acc0[e], a1 = acc1[e];
#pragma unroll
      for (int m = 0; m < 8; ++m) {
        float4 wq = *(const float4*)&wrow[4 * m];
        a0 = fmaf(xr0[m].x, wq.x, a0);
        a0 = fmaf(xr0[m].y, wq.y, a0);
        a0 = fmaf(xr0[m].z, wq.z, a0);
        a0 = fmaf(xr0[m].w, wq.w, a0);
        a1 = fmaf(xr1[m].x, wq.x, a1);
        a1 = fmaf(xr1[m].y, wq.y, a1);
        a1 = fmaf(xr1[m].z, wq.z, a1);
        a1 = fmaf(xr1[m].w, wq.w, a1);
      }
      acc0[e] = a0;
      acc1[e] = a1;
    }
    if (c + 1 < NCH) {
      const int nxb = ((c + 1) & 1) * XBUF;
      const int nwb = WOFF + ((c + 1) & 1) * WBUF;
      *(float4*)&smem[nxb + sr * XSTR + sc] = rx0;
      *(float4*)&smem[nxb + (sr + 64) * XSTR + sc] = rx1;
      *(float4*)&smem[nwb + sr * XSTR + sc] = rw;
    }
    __syncthreads();
  }

#pragma unroll
  for (int e = 0; e < 8; ++e) {
    smem[L * LG_STRIDE + wv * 8 + e] = acc0[e];
    smem[(L + 64) * LG_STRIDE + wv * 8 + e] = acc1[e];
  }
  if (tid < NEXP) hist[tid] = 0;
  __syncthreads();

  if (tid < TTILE) {
    const int t = tid;
    const float* Lg = &smem[t * LG_STRIDE];
    float m1 = Lg[0];
    int i1 = 0;
    for (int e = 1; e < NEXP; ++e) {
      float v = Lg[e];
      if (v > m1) { m1 = v; i1 = e; }
    }
    float m2 = -3.4e38f;
    int i2 = 0;
    for (int e = 0; e < NEXP; ++e) {
      if (e == i1) continue;
      float v = Lg[e];
      if (v > m2) { m2 = v; i2 = e; }
    }
    float s = 0.f;
    for (int e = 0; e < NEXP; ++e) s += expf(Lg[e] - m1);
    float p1 = expf(Lg[i1] - m1) / s;
    float p2 = expf(Lg[i2] - m1) / s;
    float wsum = p1 + p2 + 1e-8f;
    float w1 = p1 / wsum;
    float w2 = p2 / wsum;
    float ent = 0.f;
    for (int e = 0; e < NEXP; ++e) {
      float p = expf(Lg[e] - m1) / s;
      ent -= p * logf(p + 1e-10f);
    }
    float lse = m1 + logf(s);
    size_t gt = (size_t)blockIdx.x * TTILE + t;
    out[OFF_IDX + gt * 2 + 0] = (float)i1;
    out[OFF_IDX + gt * 2 + 1] = (float)i2;
    out[OFF_W + gt * 2 + 0] = w1;
    out[OFF_W + gt * 2 + 1] = w2;
    out[OFF_CONF + gt] = fmaxf(w1, w2);
    atomicAdd(&hist[i1], 1u);
    atomicAdd(&hist[i2], 1u);
    float zv = lse, ev = ent;
#pragma unroll
    for (int o = 32; o > 0; o >>= 1) {
      zv += __shfl_down(zv, o);
      ev += __shfl_down(ev, o);
    }
    if ((tid & 63) == 0) {
      atomicAdd(&ws->z_sum, (double)zv);
      atomicAdd(&ws->ent_sum, (double)ev);
    }
  }
  __syncthreads();
  if (tid < NEXP) atomicAdd(&ws->counts[tid], hist[tid]);
}

__global__ void router_final(float* __restrict__ out, RouterWS* __restrict__ ws) {
  int e = threadIdx.x;  // 64 threads
  float c = (float)ws->counts[e];
  out[OFF_CNT + e] = c;
  float over = fmaxf(c - 1280.f, 0.f);   // capacity = int(1.25*32768/64*2)
  float ld = c / 65536.f - (1.f / 64.f);
  float so = over, sv = ld * ld;
#pragma unroll
  for (int o = 32; o > 0; o >>= 1) {
    so += __shfl_down(so, o);
    sv += __shfl_down(sv, o);
  }
  if (e == 0) {
    out[OFF_OVF] = so / 32768.f * 100.f;
    out[OFF_VAR] = sv / 64.f;
    out[OFF_ZL] = (float)(ws->z_sum / 32768.0 * 0.01);
    out[OFF_ENT] = (float)(ws->ent_sum / 32768.0);
  }
}

extern "C" void kernel_launch(void* const* d_in, const int* in_sizes, int n_in,
                              void* d_out, int out_size, void* d_ws, size_t ws_size,
                              hipStream_t stream) {
  const float* x = (const float*)d_in[0];   // hidden_states [4,8192,2048] f32
  const float* w = (const float*)d_in[1];   // gate_weight [64,2048] f32
  float* out = (float*)d_out;
  RouterWS* ws = (RouterWS*)d_ws;

  (void)hipMemsetAsync(d_ws, 0, sizeof(RouterWS), stream);
  if (ws_size >= (size_t)WS_NEEDED) {
    _Float16* wp = (_Float16*)((char*)d_ws + WS_PLANES_OFF);
    hipLaunchKernelGGL(convert_w, dim3(64), dim3(256), 0, stream, w, wp);
    hipLaunchKernelGGL(router_mfma, dim3(NTOK / 64), dim3(256), 0, stream,
                       x, wp, out, ws);
  } else {
    hipLaunchKernelGGL(router_fp32, dim3(NTOK / TTILE), dim3(512), 0, stream,
                       x, w, out, ws);
  }
  hipLaunchKernelGGL(router_final, dim3(1), dim3(64), 0, stream, out, ws);
}

// Round 14
// 75.389 us; speedup vs baseline: 1.3924x; 1.3924x over previous
//
#include <hip/hip_runtime.h>

// TopKRouter: N=32768 tokens, D=2048, E=64, K=2.
// R14 = R12 + counted-vmcnt software pipeline (T3/T4):
//  - x AND w staged HBM/L2 -> LDS via global_load_lds, 4-deep ring
//    (16KB/buf: 8KB x + 8KB w), stage(s+3) issued at step s.
//  - end-of-step sync = asm s_waitcnt vmcnt(8) + raw s_barrier +
//    sched_barrier(0): never drains the x stream (T4). Tail: 4, 0.
//  - x LDS layout float4-XOR swizzled (pre-swizzled global source, linear
//    dest): conflict-free ds_read_b128. w fragment-ordered (conflict-free).
//  - fp16x2-split MFMA (hh,hl,lh,ll, K ascending) == R12 bit-identical.

#define NTOK 32768
#define DDIM 2048
#define NEXP 64
#define NKS 64              // K steps of 32
#define LG_STRIDE 68        // 64 + 4 pad

#define OFF_IDX 0
#define OFF_W 65536
#define OFF_CNT 131072
#define OFF_OVF 131136
#define OFF_ZL 131137
#define OFF_ENT 131138
#define OFF_VAR 131139
#define OFF_CONF 131140

#define WS_PLANES_OFF 1024
#define WS_NEEDED (WS_PLANES_OFF + NKS * 8192)  // 1 KB + 512 KB

struct RouterWS {
  unsigned int counts[NEXP];
  double z_sum;
  double ent_sum;
};

typedef _Float16 half8 __attribute__((ext_vector_type(8)));
typedef float floatx4 __attribute__((ext_vector_type(4)));

typedef __attribute__((address_space(1))) void v1_t;
typedef __attribute__((address_space(3))) void v3_t;
__device__ __forceinline__ void cp16(const void* g, void* l) {
  __builtin_amdgcn_global_load_lds((v1_t*)g, (v3_t*)l, 16, 0, 0);
}

// ---- prologue: split w*256 into 2 fp16 planes, fragment-ordered ----
// plane layout (halves): [s][p][t][l][8] ; lane l of etile t covers
// w[e=16t+(l&15)][k=32s+(l>>4)*8 .. +7].
__global__ void convert_w(const float* __restrict__ w, _Float16* __restrict__ wp) {
  int tid = blockIdx.x * 256 + threadIdx.x;  // 0..16383
  int l = tid & 63;
  int t = (tid >> 6) & 3;
  int s = tid >> 8;
  int e = 16 * t + (l & 15);
  int k0 = 32 * s + (l >> 4) * 8;
  const float* src = w + (size_t)e * DDIM + k0;
  half8 h, lo;
#pragma unroll
  for (int i = 0; i < 8; ++i) {
    float v = src[i] * 256.0f;
    _Float16 hh = (_Float16)v;
    h[i] = hh;
    lo[i] = (_Float16)(v - (float)hh);
  }
  size_t base = (size_t)s * 4096 + ((size_t)t * 64 + l) * 8;
  *(half8*)(wp + base) = h;
  *(half8*)(wp + base + 2048) = lo;  // plane 1
}

// ---- main MFMA kernel ----
__global__ __launch_bounds__(256, 2) void router_mfma(
    const float* __restrict__ x, const _Float16* __restrict__ wp,
    float* __restrict__ out, RouterWS* __restrict__ ws) {
  // 4 ring buffers x 16KB: [0,8K) x-tile (swizzled), [8K,12K) w hi, [12K,16K) w lo.
  // After the K loop, lg[64][68] (17.4KB) aliases the front.
  __shared__ __align__(16) char smem[65536];
  __shared__ unsigned int hist[NEXP];

  const int tid = threadIdx.x;                              // 0..255
  const int l = tid & 63;
  const int wv = __builtin_amdgcn_readfirstlane(tid >> 6);  // mtile 0..3
  const int r = l & 15;                                     // token row / expert col
  const int g = l >> 4;                                     // k-group

  const int tokb = blockIdx.x * 64;
  const float* xg = x + (size_t)tokb * DDIM;

  // staging constants: thread stages x slots tid (rows 0..31) and tid+256
  // (rows 32..63); slot i = row*8 + (j ^ (row&7)) float4s, source pre-swizzled.
  const int srow0 = tid >> 3;
  const int srow1 = srow0 + 32;
  const int sj = tid & 7;
  const size_t gx0 = (size_t)srow0 * DDIM + 4 * (sj ^ (srow0 & 7));
  const size_t gx1 = (size_t)srow1 * DDIM + 4 * (sj ^ (srow1 & 7));

  // read constants: lane (r,g) of wave wv reads row=wv*16+r, float4 cols 2g,2g+1
  const int row = wv * 16 + r;
  const int rs = row & 7;
  const int so0 = 16 * (row * 8 + ((2 * g) ^ rs));
  const int so1 = 16 * (row * 8 + ((2 * g + 1) ^ rs));
  const int wlo = 16 * l;

  floatx4 acc[4];
#pragma unroll
  for (int t = 0; t < 4; ++t) {
    floatx4 z = {0.f, 0.f, 0.f, 0.f};
    acc[t] = z;
  }

#define STAGE(S, BUF)                                                          \
  {                                                                            \
    char* bb_ = smem + (BUF) * 16384;                                          \
    cp16(xg + (size_t)(S) * 32 + gx0, bb_ + tid * 16);                         \
    cp16(xg + (size_t)(S) * 32 + gx1, bb_ + 4096 + tid * 16);                  \
    const char* wsrc_ = (const char*)wp + (size_t)(S) * 8192 + tid * 16;       \
    cp16(wsrc_, bb_ + 8192 + tid * 16);                                        \
    cp16(wsrc_ + 4096, bb_ + 12288 + tid * 16);                                \
  }

#define WAITBAR(NW)                                                            \
  asm volatile("s_waitcnt vmcnt(" #NW ")\n\ts_barrier" ::: "memory");          \
  __builtin_amdgcn_sched_barrier(0);

#define CVT8(X0, X1, XH, XL)                                                   \
  {                                                                            \
    float vv[8] = {X0.x, X0.y, X0.z, X0.w, X1.x, X1.y, X1.z, X1.w};            \
    _Pragma("unroll") for (int i = 0; i < 8; ++i) {                            \
      _Float16 hh = (_Float16)vv[i];                                           \
      XH[i] = hh;                                                              \
      XL[i] = (_Float16)(vv[i] - (float)hh);                                   \
    }                                                                          \
  }

#define COMPUTE(BUF)                                                           \
  const char* bb = smem + (BUF) * 16384;                                       \
  float4 xq0 = *(const float4*)(bb + so0);                                     \
  float4 xq1 = *(const float4*)(bb + so1);                                     \
  half8 xh, xl;                                                                \
  CVT8(xq0, xq1, xh, xl);                                                      \
  _Pragma("unroll") for (int t = 0; t < 4; ++t) {                              \
    half8 wh = *(const half8*)(bb + 8192 + 1024 * t + wlo);                    \
    half8 wl = *(const half8*)(bb + 12288 + 1024 * t + wlo);                   \
    acc[t] = __builtin_amdgcn_mfma_f32_16x16x32_f16(xh, wh, acc[t], 0, 0, 0);  \
    acc[t] = __builtin_amdgcn_mfma_f32_16x16x32_f16(xh, wl, acc[t], 0, 0, 0);  \
    acc[t] = __builtin_amdgcn_mfma_f32_16x16x32_f16(xl, wh, acc[t], 0, 0, 0);  \
    acc[t] = __builtin_amdgcn_mfma_f32_16x16x32_f16(xl, wl, acc[t], 0, 0, 0);  \
  }

#define STEP(S, BUF, NW)                                                       \
  {                                                                            \
    STAGE((S) + 3, (((S) + 3) & 3));                                           \
    COMPUTE(BUF)                                                               \
    WAITBAR(NW)                                                                \
  }
#define STEPN(S, BUF, NW)  /* tail: no stage */                                \
  {                                                                            \
    COMPUTE(BUF)                                                               \
    WAITBAR(NW)                                                                \
  }

  // prologue: stages 0,1,2 in flight; wait until stage 0 lands.
  STAGE(0, 0)
  STAGE(1, 1)
  STAGE(2, 2)
  if (tid < NEXP) hist[tid] = 0;
  WAITBAR(8)

  for (int ss = 0; ss < 60; ss += 4) {  // ss = 0..56; steps 0..59
    STEP(ss, 0, 8)
    STEP(ss + 1, 1, 8)
    STEP(ss + 2, 2, 8)
    STEP(ss + 3, 3, 8)
  }
  STEP(60, 0, 8)    // stages 63
  STEPN(61, 1, 4)   // need stage 62 done
  STEPN(62, 2, 0)   // need stage 63 done
  {                 // step 63: nothing outstanding
    COMPUTE(3)
  }
  __syncthreads();

#undef STEP
#undef STEPN
#undef COMPUTE
#undef CVT8
#undef WAITBAR
#undef STAGE

  // C layout (HW-verified): col = lane&15, row = (lane>>4)*4 + j.
  // lg[token][expert], token = wv*16 + g*4 + j, expert = 16t + r. Scale 1/256.
  float* lg = (float*)smem;
#pragma unroll
  for (int t = 0; t < 4; ++t)
#pragma unroll
    for (int j = 0; j < 4; ++j)
      lg[(wv * 16 + g * 4 + j) * LG_STRIDE + 16 * t + r] = acc[t][j] * 0.00390625f;
  __syncthreads();

  if (tid < 64) {  // wave 0: one token per lane, serial over 64 experts
    const int t = tid;
    const float* Lg = &lg[t * LG_STRIDE];

    float m1 = Lg[0];
    int i1 = 0;
    for (int e = 1; e < NEXP; ++e) {
      float v = Lg[e];
      if (v > m1) { m1 = v; i1 = e; }  // strict > keeps lowest index on ties
    }
    float m2 = -3.4e38f;
    int i2 = 0;
    for (int e = 0; e < NEXP; ++e) {
      if (e == i1) continue;
      float v = Lg[e];
      if (v > m2) { m2 = v; i2 = e; }
    }

    float s = 0.f;
    for (int e = 0; e < NEXP; ++e) s += expf(Lg[e] - m1);
    float p1 = expf(Lg[i1] - m1) / s;
    float p2 = expf(Lg[i2] - m1) / s;
    float wsum = p1 + p2 + 1e-8f;
    float w1 = p1 / wsum;
    float w2 = p2 / wsum;

    float ent = 0.f;
    for (int e = 0; e < NEXP; ++e) {
      float p = expf(Lg[e] - m1) / s;
      ent -= p * logf(p + 1e-10f);
    }
    float lse = m1 + logf(s);

    size_t gt = (size_t)blockIdx.x * 64 + t;
    out[OFF_IDX + gt * 2 + 0] = (float)i1;
    out[OFF_IDX + gt * 2 + 1] = (float)i2;
    out[OFF_W + gt * 2 + 0] = w1;
    out[OFF_W + gt * 2 + 1] = w2;
    out[OFF_CONF + gt] = fmaxf(w1, w2);

    atomicAdd(&hist[i1], 1u);
    atomicAdd(&hist[i2], 1u);

    float zv = lse, ev = ent;
#pragma unroll
    for (int o = 32; o > 0; o >>= 1) {
      zv += __shfl_down(zv, o);
      ev += __shfl_down(ev, o);
    }
    if (t == 0) {
      atomicAdd(&ws->z_sum, (double)zv);
      atomicAdd(&ws->ent_sum, (double)ev);
    }
  }
  __syncthreads();
  if (tid < NEXP) atomicAdd(&ws->counts[tid], hist[tid]);
}

// ---- fp32 fallback (R10) if ws too small for planes ----
#define TTILE 128
#define KB 32
#define NCH (DDIM / KB)
#define XSTR 36
#define XBUF (TTILE * XSTR)
#define WBUF (NEXP * XSTR)
#define WOFF (2 * XBUF)

__global__ __launch_bounds__(512, 4) void router_fp32(
    const float* __restrict__ x, const float* __restrict__ w,
    float* __restrict__ out, RouterWS* __restrict__ ws) {
  __shared__ float smem[2 * XBUF + 2 * WBUF];
  __shared__ unsigned int hist[NEXP];

  const int tid = threadIdx.x;
  const int L = tid & 63;
  const int wv = __builtin_amdgcn_readfirstlane(tid >> 6);
  const float* xg = x + (size_t)blockIdx.x * TTILE * DDIM;
  const int sr = tid >> 3;
  const int sc = (tid & 7) * 4;

  float4 rx0 = *(const float4*)(xg + (size_t)sr * DDIM + sc);
  float4 rx1 = *(const float4*)(xg + (size_t)(sr + 64) * DDIM + sc);
  float4 rw = *(const float4*)(w + (size_t)sr * DDIM + sc);
  *(float4*)&smem[sr * XSTR + sc] = rx0;
  *(float4*)&smem[(sr + 64) * XSTR + sc] = rx1;
  *(float4*)&smem[WOFF + sr * XSTR + sc] = rw;

  float acc0[8], acc1[8];
#pragma unroll
  for (int e = 0; e < 8; ++e) { acc0[e] = 0.f; acc1[e] = 0.f; }
  __syncthreads();

  for (int c = 0; c < NCH; ++c) {
    const int cxb = (c & 1) * XBUF;
    const int cwb = WOFF + (c & 1) * WBUF;
    if (c + 1 < NCH) {
      int k0 = (c + 1) * KB;
      rx0 = *(const float4*)(xg + (size_t)sr * DDIM + k0 + sc);
      rx1 = *(const float4*)(xg + (size_t)(sr + 64) * DDIM + k0 + sc);
      rw = *(const float4*)(w + (size_t)sr * DDIM + k0 + sc);
    }
    float4 xr0[8], xr1[8];
#pragma unroll
    for (int m = 0; m < 8; ++m) {
      xr0[m] = *(const float4*)&smem[cxb + L * XSTR + 4 * m];
      xr1[m] = *(const float4*)&smem[cxb + (L + 64) * XSTR + 4 * m];
    }
#pragma unroll
    for (int e = 0; e < 8; ++e) {
      const float* wrow = &smem[cwb + (8 * wv + e) * XSTR];
      float a0 = acc0[e], a1 = acc1[e];
#pragma unroll
      for (int m = 0; m < 8; ++m) {
        float4 wq = *(const float4*)&wrow[4 * m];
        a0 = fmaf(xr0[m].x, wq.x, a0);
        a0 = fmaf(xr0[m].y, wq.y, a0);
        a0 = fmaf(xr0[m].z, wq.z, a0);
        a0 = fmaf(xr0[m].w, wq.w, a0);
        a1 = fmaf(xr1[m].x, wq.x, a1);
        a1 = fmaf(xr1[m].y, wq.y, a1);
        a1 = fmaf(xr1[m].z, wq.z, a1);
        a1 = fmaf(xr1[m].w, wq.w, a1);
      }
      acc0[e] = a0;
      acc1[e] = a1;
    }
    if (c + 1 < NCH) {
      const int nxb = ((c + 1) & 1) * XBUF;
      const int nwb = WOFF + ((c + 1) & 1) * WBUF;
      *(float4*)&smem[nxb + sr * XSTR + sc] = rx0;
      *(float4*)&smem[nxb + (sr + 64) * XSTR + sc] = rx1;
      *(float4*)&smem[nwb + sr * XSTR + sc] = rw;
    }
    __syncthreads();
  }

#pragma unroll
  for (int e = 0; e < 8; ++e) {
    smem[L * LG_STRIDE + wv * 8 + e] = acc0[e];
    smem[(L + 64) * LG_STRIDE + wv * 8 + e] = acc1[e];
  }
  if (tid < NEXP) hist[tid] = 0;
  __syncthreads();

  if (tid < TTILE) {
    const int t = tid;
    const float* Lg = &smem[t * LG_STRIDE];
    float m1 = Lg[0];
    int i1 = 0;
    for (int e = 1; e < NEXP; ++e) {
      float v = Lg[e];
      if (v > m1) { m1 = v; i1 = e; }
    }
    float m2 = -3.4e38f;
    int i2 = 0;
    for (int e = 0; e < NEXP; ++e) {
      if (e == i1) continue;
      float v = Lg[e];
      if (v > m2) { m2 = v; i2 = e; }
    }
    float s = 0.f;
    for (int e = 0; e < NEXP; ++e) s += expf(Lg[e] - m1);
    float p1 = expf(Lg[i1] - m1) / s;
    float p2 = expf(Lg[i2] - m1) / s;
    float wsum = p1 + p2 + 1e-8f;
    float w1 = p1 / wsum;
    float w2 = p2 / wsum;
    float ent = 0.f;
    for (int e = 0; e < NEXP; ++e) {
      float p = expf(Lg[e] - m1) / s;
      ent -= p * logf(p + 1e-10f);
    }
    float lse = m1 + logf(s);
    size_t gt = (size_t)blockIdx.x * TTILE + t;
    out[OFF_IDX + gt * 2 + 0] = (float)i1;
    out[OFF_IDX + gt * 2 + 1] = (float)i2;
    out[OFF_W + gt * 2 + 0] = w1;
    out[OFF_W + gt * 2 + 1] = w2;
    out[OFF_CONF + gt] = fmaxf(w1, w2);
    atomicAdd(&hist[i1], 1u);
    atomicAdd(&hist[i2], 1u);
    float zv = lse, ev = ent;
#pragma unroll
    for (int o = 32; o > 0; o >>= 1) {
      zv += __shfl_down(zv, o);
      ev += __shfl_down(ev, o);
    }
    if ((tid & 63) == 0) {
      atomicAdd(&ws->z_sum, (double)zv);
      atomicAdd(&ws->ent_sum, (double)ev);
    }
  }
  __syncthreads();
  if (tid < NEXP) atomicAdd(&ws->counts[tid], hist[tid]);
}

__global__ void router_final(float* __restrict__ out, RouterWS* __restrict__ ws) {
  int e = threadIdx.x;  // 64 threads
  float c = (float)ws->counts[e];
  out[OFF_CNT + e] = c;
  float over = fmaxf(c - 1280.f, 0.f);   // capacity = int(1.25*32768/64*2)
  float ld = c / 65536.f - (1.f / 64.f);
  float so = over, sv = ld * ld;
#pragma unroll
  for (int o = 32; o > 0; o >>= 1) {
    so += __shfl_down(so, o);
    sv += __shfl_down(sv, o);
  }
  if (e == 0) {
    out[OFF_OVF] = so / 32768.f * 100.f;
    out[OFF_VAR] = sv / 64.f;
    out[OFF_ZL] = (float)(ws->z_sum / 32768.0 * 0.01);
    out[OFF_ENT] = (float)(ws->ent_sum / 32768.0);
  }
}

extern "C" void kernel_launch(void* const* d_in, const int* in_sizes, int n_in,
                              void* d_out, int out_size, void* d_ws, size_t ws_size,
                              hipStream_t stream) {
  const float* x = (const float*)d_in[0];   // hidden_states [4,8192,2048] f32
  const float* w = (const float*)d_in[1];   // gate_weight [64,2048] f32
  float* out = (float*)d_out;
  RouterWS* ws = (RouterWS*)d_ws;

  (void)hipMemsetAsync(d_ws, 0, sizeof(RouterWS), stream);
  if (ws_size >= (size_t)WS_NEEDED) {
    _Float16* wp = (_Float16*)((char*)d_ws + WS_PLANES_OFF);
    hipLaunchKernelGGL(convert_w, dim3(64), dim3(256), 0, stream, w, wp);
    hipLaunchKernelGGL(router_mfma, dim3(NTOK / 64), dim3(256), 0, stream,
                       x, wp, out, ws);
  } else {
    hipLaunchKernelGGL(router_fp32, dim3(NTOK / TTILE), dim3(512), 0, stream,
                       x, w, out, ws);
  }
  hipLaunchKernelGGL(router_final, dim3(1), dim3(64), 0, stream, out, ws);
}